// Round 1
// baseline (1054.371 us; speedup 1.0000x reference)
//
#include <hip/hip_runtime.h>
#include <math.h>

#define SEQ 2048
#define NBATCH 2
#define DEMB 1024
#define NH 16
#define HD 64
#define NROWS (NBATCH * SEQ) // 4096

// ============================================================================
// QKV projection: X[4096][1024] @ W^T for each of Wq,Wk,Wv ([out][in] layout).
// Output written directly in [b, h, s, d] layout for attention.
// Tile 128x128, BK=16, 256 threads, 8x8 microtile (split 4+4 register layout).
// ============================================================================
__global__ __launch_bounds__(256) void qkv_gemm(
    const float* __restrict__ X,
    const float* __restrict__ Wq, const float* __restrict__ Wk,
    const float* __restrict__ Wv,
    float* __restrict__ Qo, float* __restrict__ Ko, float* __restrict__ Vo)
{
    __shared__ float As[16][132]; // [k][m], pad 132 keeps float4 alignment
    __shared__ float Bs[16][132]; // [k][n]

    const int m0   = blockIdx.y * 128;
    const int nblk = blockIdx.x;          // 0..23
    const int which = nblk >> 3;          // 8 n-tiles per weight
    const int n0   = (nblk & 7) * 128;
    const float* __restrict__ W  = (which == 0) ? Wq : (which == 1) ? Wk : Wv;
    float* __restrict__ Out      = (which == 0) ? Qo : (which == 1) ? Ko : Vo;

    const int tid = threadIdx.x;
    const int tx = tid & 15, ty = tid >> 4;
    const int lrow = tid >> 1;        // 0..127
    const int lcg  = (tid & 1) * 2;   // colgroup base 0 or 2

    float acc[8][8];
#pragma unroll
    for (int i = 0; i < 8; ++i)
#pragma unroll
        for (int j = 0; j < 8; ++j) acc[i][j] = 0.f;

    for (int k0 = 0; k0 < DEMB; k0 += 16) {
        // ---- stage A,B panels into LDS (transposed to [k][mn]) ----
#pragma unroll
        for (int u = 0; u < 2; ++u) {
            const int cg = lcg + u; // 0..3 (4 floats each)
            const float4 va = *(const float4*)&X[(m0 + lrow) * DEMB + k0 + cg * 4];
            As[cg * 4 + 0][lrow] = va.x;
            As[cg * 4 + 1][lrow] = va.y;
            As[cg * 4 + 2][lrow] = va.z;
            As[cg * 4 + 3][lrow] = va.w;
            const float4 vb = *(const float4*)&W[(n0 + lrow) * DEMB + k0 + cg * 4];
            Bs[cg * 4 + 0][lrow] = vb.x;
            Bs[cg * 4 + 1][lrow] = vb.y;
            Bs[cg * 4 + 2][lrow] = vb.z;
            Bs[cg * 4 + 3][lrow] = vb.w;
        }
        __syncthreads();
#pragma unroll
        for (int kk = 0; kk < 16; ++kk) {
            const float4 a0 = *(const float4*)&As[kk][ty * 4];
            const float4 a1 = *(const float4*)&As[kk][64 + ty * 4];
            const float4 b0 = *(const float4*)&Bs[kk][tx * 4];
            const float4 b1 = *(const float4*)&Bs[kk][64 + tx * 4];
            const float a[8] = {a0.x, a0.y, a0.z, a0.w, a1.x, a1.y, a1.z, a1.w};
            const float b[8] = {b0.x, b0.y, b0.z, b0.w, b1.x, b1.y, b1.z, b1.w};
#pragma unroll
            for (int i = 0; i < 8; ++i)
#pragma unroll
                for (int j = 0; j < 8; ++j) acc[i][j] += a[i] * b[j];
        }
        __syncthreads();
    }

    // ---- epilogue: write in [b,h,s,d] layout ----
#pragma unroll
    for (int i = 0; i < 8; ++i) {
        const int row = (i < 4) ? (ty * 4 + i) : (64 + ty * 4 + (i - 4));
        const int m = m0 + row;
        const int b = m >> 11;        // /2048
        const int s = m & 2047;
#pragma unroll
        for (int jg = 0; jg < 2; ++jg) {
            const int nl = n0 + jg * 64 + tx * 4;
            const int h = nl >> 6;
            const int d = nl & 63;
            const float4 v4 = make_float4(acc[i][jg * 4 + 0], acc[i][jg * 4 + 1],
                                          acc[i][jg * 4 + 2], acc[i][jg * 4 + 3]);
            *(float4*)&Out[(((size_t)b * NH + h) * SEQ + s) * HD + d] = v4;
        }
    }
}

// ============================================================================
// Flash-style causal attention, fp32. One block = one 64-row Q tile of one
// (b,h). 256 threads as 16x16, each owns a 4x4 of the 64x64 S tile.
// Row reductions via __shfl_xor within 16-lane groups. Softmax scale (1/8)
// folded into Q load.
// ============================================================================
__global__ __launch_bounds__(256) void flash_attn(
    const float* __restrict__ Q, const float* __restrict__ K,
    const float* __restrict__ V, float* __restrict__ ctx)
{
    __shared__ float Qs[HD][68]; // [d][r]
    __shared__ float Ks[HD][68]; // [d][c]
    __shared__ float Vs[64][68]; // [kvrow][d]
    __shared__ float Ps[64][68]; // [r][kv]

    const int qt = blockIdx.x;   // 0..31
    const int h  = blockIdx.y;
    const int b  = blockIdx.z;
    const size_t base = ((size_t)(b * NH + h)) * SEQ * HD;

    const int tid = threadIdx.x;
    const int tx = tid & 15, ty = tid >> 4;

    // ---- load Q tile (scaled by 1/sqrt(HD)) into Qs[d][r] ----
#pragma unroll
    for (int u = 0; u < 4; ++u) {
        const int f = u * 256 + tid;      // 0..1023
        const int r = f >> 4;             // 0..63
        const int dc = (f & 15) * 4;      // 0..60
        const float4 q4 = *(const float4*)&Q[base + (size_t)(qt * 64 + r) * HD + dc];
        Qs[dc + 0][r] = q4.x * 0.125f;
        Qs[dc + 1][r] = q4.y * 0.125f;
        Qs[dc + 2][r] = q4.z * 0.125f;
        Qs[dc + 3][r] = q4.w * 0.125f;
    }

    float m_r[4], l_r[4], o[4][4];
#pragma unroll
    for (int i = 0; i < 4; ++i) {
        m_r[i] = -1e30f;
        l_r[i] = 0.f;
#pragma unroll
        for (int j = 0; j < 4; ++j) o[i][j] = 0.f;
    }

    for (int j = 0; j <= qt; ++j) {
        // prefetch K/V tile into registers (overlaps with prev PV)
        float4 kreg[4], vreg[4];
        int rr[4], dd[4];
#pragma unroll
        for (int u = 0; u < 4; ++u) {
            const int f = u * 256 + tid;
            rr[u] = f >> 4;
            dd[u] = (f & 15) * 4;
            kreg[u] = *(const float4*)&K[base + (size_t)(j * 64 + rr[u]) * HD + dd[u]];
            vreg[u] = *(const float4*)&V[base + (size_t)(j * 64 + rr[u]) * HD + dd[u]];
        }
        __syncthreads(); // prev iteration's PV reads of Ks/Vs/Ps are done
#pragma unroll
        for (int u = 0; u < 4; ++u) {
            Ks[dd[u] + 0][rr[u]] = kreg[u].x;
            Ks[dd[u] + 1][rr[u]] = kreg[u].y;
            Ks[dd[u] + 2][rr[u]] = kreg[u].z;
            Ks[dd[u] + 3][rr[u]] = kreg[u].w;
            *(float4*)&Vs[rr[u]][dd[u]] = vreg[u];
        }
        __syncthreads();

        // ---- S = (Q/8) K^T : 4x4 per thread ----
        float s[4][4];
#pragma unroll
        for (int i = 0; i < 4; ++i)
#pragma unroll
            for (int jj = 0; jj < 4; ++jj) s[i][jj] = 0.f;
#pragma unroll 16
        for (int d = 0; d < HD; ++d) {
            const float4 a4 = *(const float4*)&Qs[d][ty * 4];
            const float4 b4 = *(const float4*)&Ks[d][tx * 4];
            const float a[4] = {a4.x, a4.y, a4.z, a4.w};
            const float bb[4] = {b4.x, b4.y, b4.z, b4.w};
#pragma unroll
            for (int i = 0; i < 4; ++i)
#pragma unroll
                for (int jj = 0; jj < 4; ++jj) s[i][jj] += a[i] * bb[jj];
        }
        // causal mask on the diagonal tile
        if (j == qt) {
#pragma unroll
            for (int i = 0; i < 4; ++i)
#pragma unroll
                for (int jj = 0; jj < 4; ++jj)
                    if (tx * 4 + jj > ty * 4 + i) s[i][jj] = -1e30f;
        }

        // ---- online softmax ----
        float nm[4], rsum[4];
#pragma unroll
        for (int i = 0; i < 4; ++i) {
            float tm = fmaxf(fmaxf(s[i][0], s[i][1]), fmaxf(s[i][2], s[i][3]));
            tm = fmaxf(tm, __shfl_xor(tm, 1, 16));
            tm = fmaxf(tm, __shfl_xor(tm, 2, 16));
            tm = fmaxf(tm, __shfl_xor(tm, 4, 16));
            tm = fmaxf(tm, __shfl_xor(tm, 8, 16));
            nm[i] = fmaxf(m_r[i], tm);
            float rs = 0.f;
#pragma unroll
            for (int jj = 0; jj < 4; ++jj) {
                const float p = __expf(s[i][jj] - nm[i]);
                s[i][jj] = p;
                rs += p;
            }
            rs += __shfl_xor(rs, 1, 16);
            rs += __shfl_xor(rs, 2, 16);
            rs += __shfl_xor(rs, 4, 16);
            rs += __shfl_xor(rs, 8, 16);
            rsum[i] = rs;
        }
#pragma unroll
        for (int i = 0; i < 4; ++i) {
            const float scale = __expf(m_r[i] - nm[i]);
            l_r[i] = l_r[i] * scale + rsum[i];
            m_r[i] = nm[i];
#pragma unroll
            for (int jj = 0; jj < 4; ++jj) o[i][jj] *= scale;
            // stage P tile
            *(float4*)&Ps[ty * 4 + i][tx * 4] =
                make_float4(s[i][0], s[i][1], s[i][2], s[i][3]);
        }
        __syncthreads();

        // ---- O += P @ V ----
#pragma unroll 4
        for (int kv0 = 0; kv0 < 64; kv0 += 4) {
            float4 pv[4], vv[4];
#pragma unroll
            for (int i = 0; i < 4; ++i) pv[i] = *(const float4*)&Ps[ty * 4 + i][kv0];
#pragma unroll
            for (int u = 0; u < 4; ++u) vv[u] = *(const float4*)&Vs[kv0 + u][tx * 4];
#pragma unroll
            for (int i = 0; i < 4; ++i) {
                const float p[4] = {pv[i].x, pv[i].y, pv[i].z, pv[i].w};
#pragma unroll
                for (int u = 0; u < 4; ++u) {
                    o[i][0] += p[u] * vv[u].x;
                    o[i][1] += p[u] * vv[u].y;
                    o[i][2] += p[u] * vv[u].z;
                    o[i][3] += p[u] * vv[u].w;
                }
            }
        }
    }

    // ---- epilogue: normalize and write ctx in [b, s, h*64+d] layout ----
#pragma unroll
    for (int i = 0; i < 4; ++i) {
        const float inv = 1.f / l_r[i];
        const int sg = qt * 64 + ty * 4 + i;
        const float4 v4 = make_float4(o[i][0] * inv, o[i][1] * inv,
                                      o[i][2] * inv, o[i][3] * inv);
        *(float4*)&ctx[((size_t)(b * SEQ + sg)) * DEMB + h * HD + tx * 4] = v4;
    }
}

// ============================================================================
// Output projection: ctx[4096][1024] @ Wo^T + bo -> out[4096][1024]
// ============================================================================
__global__ __launch_bounds__(256) void out_gemm(
    const float* __restrict__ Xc, const float* __restrict__ Wo,
    const float* __restrict__ bo, float* __restrict__ Out)
{
    __shared__ float As[16][132];
    __shared__ float Bs[16][132];
    const int m0 = blockIdx.y * 128;
    const int n0 = blockIdx.x * 128;

    const int tid = threadIdx.x;
    const int tx = tid & 15, ty = tid >> 4;
    const int lrow = tid >> 1;
    const int lcg  = (tid & 1) * 2;

    float acc[8][8];
#pragma unroll
    for (int i = 0; i < 8; ++i)
#pragma unroll
        for (int j = 0; j < 8; ++j) acc[i][j] = 0.f;

    for (int k0 = 0; k0 < DEMB; k0 += 16) {
#pragma unroll
        for (int u = 0; u < 2; ++u) {
            const int cg = lcg + u;
            const float4 va = *(const float4*)&Xc[(m0 + lrow) * DEMB + k0 + cg * 4];
            As[cg * 4 + 0][lrow] = va.x;
            As[cg * 4 + 1][lrow] = va.y;
            As[cg * 4 + 2][lrow] = va.z;
            As[cg * 4 + 3][lrow] = va.w;
            const float4 vb = *(const float4*)&Wo[(n0 + lrow) * DEMB + k0 + cg * 4];
            Bs[cg * 4 + 0][lrow] = vb.x;
            Bs[cg * 4 + 1][lrow] = vb.y;
            Bs[cg * 4 + 2][lrow] = vb.z;
            Bs[cg * 4 + 3][lrow] = vb.w;
        }
        __syncthreads();
#pragma unroll
        for (int kk = 0; kk < 16; ++kk) {
            const float4 a0 = *(const float4*)&As[kk][ty * 4];
            const float4 a1 = *(const float4*)&As[kk][64 + ty * 4];
            const float4 b0 = *(const float4*)&Bs[kk][tx * 4];
            const float4 b1 = *(const float4*)&Bs[kk][64 + tx * 4];
            const float a[8] = {a0.x, a0.y, a0.z, a0.w, a1.x, a1.y, a1.z, a1.w};
            const float b[8] = {b0.x, b0.y, b0.z, b0.w, b1.x, b1.y, b1.z, b1.w};
#pragma unroll
            for (int i = 0; i < 8; ++i)
#pragma unroll
                for (int j = 0; j < 8; ++j) acc[i][j] += a[i] * b[j];
        }
        __syncthreads();
    }

#pragma unroll
    for (int i = 0; i < 8; ++i) {
        const int row = (i < 4) ? (ty * 4 + i) : (64 + ty * 4 + (i - 4));
        const int m = m0 + row;
#pragma unroll
        for (int jg = 0; jg < 2; ++jg) {
            const int n = n0 + jg * 64 + tx * 4;
            const float4 bias = *(const float4*)&bo[n];
            const float4 v4 = make_float4(acc[i][jg * 4 + 0] + bias.x,
                                          acc[i][jg * 4 + 1] + bias.y,
                                          acc[i][jg * 4 + 2] + bias.z,
                                          acc[i][jg * 4 + 3] + bias.w);
            *(float4*)&Out[(size_t)m * DEMB + n] = v4;
        }
    }
}

extern "C" void kernel_launch(void* const* d_in, const int* in_sizes, int n_in,
                              void* d_out, int out_size, void* d_ws, size_t ws_size,
                              hipStream_t stream) {
    const float* x  = (const float*)d_in[0];
    const float* Wq = (const float*)d_in[1];
    const float* Wk = (const float*)d_in[2];
    const float* Wv = (const float*)d_in[3];
    const float* Wo = (const float*)d_in[4];
    const float* bo = (const float*)d_in[5];
    float* out = (float*)d_out;

    const size_t NELEM = (size_t)NROWS * DEMB; // 4194304 floats = 16 MB
    float* ws = (float*)d_ws;
    float* Q   = ws;
    float* K   = ws + NELEM;
    float* V   = ws + 2 * NELEM;
    float* ctx = ws + 3 * NELEM;

    qkv_gemm<<<dim3(24, 32), 256, 0, stream>>>(x, Wq, Wk, Wv, Q, K, V);
    flash_attn<<<dim3(SEQ / 64, NH, NBATCH), 256, 0, stream>>>(Q, K, V, ctx);
    out_gemm<<<dim3(8, 32), 256, 0, stream>>>(ctx, Wo, bo, out);
}

// Round 2
// 691.944 us; speedup vs baseline: 1.5238x; 1.5238x over previous
//
#include <hip/hip_runtime.h>
#include <math.h>

#define SEQ 2048
#define NBATCH 2
#define DEMB 1024
#define NH 16
#define HD 64
#define NROWS (NBATCH * SEQ) // 4096

typedef __attribute__((ext_vector_type(8))) short short8;   // 8 bf16 (4 VGPR)
typedef __attribute__((ext_vector_type(4))) float f32x4;    // MFMA acc

__device__ __forceinline__ unsigned short f2bf(float f) {
    unsigned int u = __float_as_uint(f);
    u = (u + 0x7FFFu + ((u >> 16) & 1u)) >> 16;   // RNE
    return (unsigned short)u;
}
__device__ __forceinline__ float bf2f(unsigned short s) {
    return __uint_as_float(((unsigned int)s) << 16);
}

// ============================================================================
// Cast fp32 inputs to bf16 working buffers. Wq is pre-scaled by 1/sqrt(HD)=0.125
// so the softmax scale is free downstream.
// ============================================================================
__global__ __launch_bounds__(256) void cast_bf16(
    const float* __restrict__ x, const float* __restrict__ wq,
    const float* __restrict__ wk, const float* __restrict__ wv,
    const float* __restrict__ wo,
    unsigned short* __restrict__ Xb, unsigned short* __restrict__ Wb,
    unsigned short* __restrict__ Wob)
{
    const int q = blockIdx.x * 256 + threadIdx.x; // quad index
    float4 v; unsigned short* dst; float sc = 1.f;
    if (q < 1048576) {                       // X: 4194304 elems
        v = ((const float4*)x)[q];
        dst = Xb + q * 4;
    } else if (q < 1835008) {                // Wq|Wk|Wv concat: 3145728 elems
        const int e = (q - 1048576) * 4;
        const int which = e >> 20;
        const int off = e & 1048575;
        const float* s = (which == 0) ? wq : (which == 1) ? wk : wv;
        v = *(const float4*)&s[off];
        sc = (which == 0) ? 0.125f : 1.f;
        dst = Wb + e;
    } else {                                 // Wo: 1048576 elems
        const int j = q - 1835008;
        v = ((const float4*)wo)[j];
        dst = Wob + j * 4;
    }
    ushort4 o;
    o.x = f2bf(v.x * sc); o.y = f2bf(v.y * sc);
    o.z = f2bf(v.z * sc); o.w = f2bf(v.w * sc);
    *(ushort4*)dst = o;
}

// ============================================================================
// bf16 MFMA NT-GEMM, m97 structure: 128x128 tile, BK=32, 256 thr / 4 waves,
// each wave 64x64 (4x4 frags of 16x16x32). LDS tiles [128][32] bf16 with XOR
// swizzle slot ^= (row>>1)&3 (write and read both swizzled -> 2-way, free).
// QKV variant: A=Xb[4096][1024], B=Wb[3072][1024]; writes Q/K/V bf16 [b,h,s,d].
// ============================================================================
__global__ __launch_bounds__(256) void gemm_qkv(
    const unsigned short* __restrict__ Xb, const unsigned short* __restrict__ Wb,
    unsigned short* __restrict__ Qb, unsigned short* __restrict__ Kb,
    unsigned short* __restrict__ Vb)
{
    __shared__ short As[128 * 32];
    __shared__ short Bs[128 * 32];

    const int tid = threadIdx.x;
    const int m0 = blockIdx.y * 128, n0 = blockIdx.x * 128;

    // staging: thread covers rows sr and sr+64, colgroup sg (8 bf16 = 16B)
    const int sr = tid >> 2, sg = tid & 3;
    const int slot = sg ^ ((sr >> 1) & 3);        // same for row sr+64
    const int st0 = sr * 32 + slot * 8;
    const int st1 = (sr + 64) * 32 + slot * 8;

    const int lane = tid & 63, w = tid >> 6;
    const int wr = w >> 1, wc = w & 1;
    const int fr = lane & 15, fq = lane >> 4;

    // fragment LDS read offsets (constant across K loop)
    int offA[4], offB[4];
#pragma unroll
    for (int m = 0; m < 4; ++m) {
        const int rA = wr * 64 + m * 16 + fr;
        offA[m] = rA * 32 + ((fq ^ ((rA >> 1) & 3)) * 8);
        const int rB = wc * 64 + m * 16 + fr;
        offB[m] = rB * 32 + ((fq ^ ((rB >> 1) & 3)) * 8);
    }

    f32x4 acc[4][4];
#pragma unroll
    for (int m = 0; m < 4; ++m)
#pragma unroll
        for (int n = 0; n < 4; ++n) acc[m][n] = (f32x4){0.f, 0.f, 0.f, 0.f};

    const unsigned short* ga0 = Xb + (m0 + sr) * 1024 + sg * 8;
    const unsigned short* ga1 = Xb + (m0 + 64 + sr) * 1024 + sg * 8;
    const unsigned short* gb0 = Wb + (n0 + sr) * 1024 + sg * 8;
    const unsigned short* gb1 = Wb + (n0 + 64 + sr) * 1024 + sg * 8;

    short8 ra0 = *(const short8*)ga0, ra1 = *(const short8*)ga1;
    short8 rb0 = *(const short8*)gb0, rb1 = *(const short8*)gb1;

    for (int k = 0; k < 32; ++k) {
        __syncthreads();
        *(short8*)&As[st0] = ra0; *(short8*)&As[st1] = ra1;
        *(short8*)&Bs[st0] = rb0; *(short8*)&Bs[st1] = rb1;
        __syncthreads();
        if (k < 31) {
            ga0 += 32; ga1 += 32; gb0 += 32; gb1 += 32;
            ra0 = *(const short8*)ga0; ra1 = *(const short8*)ga1;
            rb0 = *(const short8*)gb0; rb1 = *(const short8*)gb1;
        }
        short8 af[4], bg[4];
#pragma unroll
        for (int m = 0; m < 4; ++m) af[m] = *(const short8*)&As[offA[m]];
#pragma unroll
        for (int n = 0; n < 4; ++n) bg[n] = *(const short8*)&Bs[offB[n]];
#pragma unroll
        for (int m = 0; m < 4; ++m)
#pragma unroll
            for (int n = 0; n < 4; ++n)
                acc[m][n] = __builtin_amdgcn_mfma_f32_16x16x32_bf16(
                    af[m], bg[n], acc[m][n], 0, 0, 0);
    }

    // epilogue: C row=(b,s), col->(which,h,d); write bf16 [b,h,s,d]
#pragma unroll
    for (int n = 0; n < 4; ++n) {
        const int col = n0 + wc * 64 + n * 16 + fr;
        const int which = col >> 10;
        const int h = (col >> 6) & 15;
        const int d = col & 63;
        unsigned short* Out = (which == 0) ? Qb : (which == 1) ? Kb : Vb;
#pragma unroll
        for (int m = 0; m < 4; ++m) {
            const int rowb = m0 + wr * 64 + m * 16 + fq * 4;
#pragma unroll
            for (int r = 0; r < 4; ++r) {
                const int row = rowb + r;
                const int b = row >> 11, s = row & 2047;
                Out[(((size_t)b * NH + h) * SEQ + s) * HD + d] =
                    f2bf(acc[m][n][r]);
            }
        }
    }
}

// ============================================================================
// O-projection: ctx_bf16[4096][1024] @ Wob^T + bo -> out fp32 [4096][1024]
// ============================================================================
__global__ __launch_bounds__(256) void gemm_out(
    const unsigned short* __restrict__ Cb, const unsigned short* __restrict__ Wob,
    const float* __restrict__ bo, float* __restrict__ Out)
{
    __shared__ short As[128 * 32];
    __shared__ short Bs[128 * 32];

    const int tid = threadIdx.x;
    const int m0 = blockIdx.y * 128, n0 = blockIdx.x * 128;
    const int sr = tid >> 2, sg = tid & 3;
    const int slot = sg ^ ((sr >> 1) & 3);
    const int st0 = sr * 32 + slot * 8;
    const int st1 = (sr + 64) * 32 + slot * 8;

    const int lane = tid & 63, w = tid >> 6;
    const int wr = w >> 1, wc = w & 1;
    const int fr = lane & 15, fq = lane >> 4;

    int offA[4], offB[4];
#pragma unroll
    for (int m = 0; m < 4; ++m) {
        const int rA = wr * 64 + m * 16 + fr;
        offA[m] = rA * 32 + ((fq ^ ((rA >> 1) & 3)) * 8);
        const int rB = wc * 64 + m * 16 + fr;
        offB[m] = rB * 32 + ((fq ^ ((rB >> 1) & 3)) * 8);
    }

    f32x4 acc[4][4];
#pragma unroll
    for (int m = 0; m < 4; ++m)
#pragma unroll
        for (int n = 0; n < 4; ++n) acc[m][n] = (f32x4){0.f, 0.f, 0.f, 0.f};

    const unsigned short* ga0 = Cb + (m0 + sr) * 1024 + sg * 8;
    const unsigned short* ga1 = Cb + (m0 + 64 + sr) * 1024 + sg * 8;
    const unsigned short* gb0 = Wob + (n0 + sr) * 1024 + sg * 8;
    const unsigned short* gb1 = Wob + (n0 + 64 + sr) * 1024 + sg * 8;

    short8 ra0 = *(const short8*)ga0, ra1 = *(const short8*)ga1;
    short8 rb0 = *(const short8*)gb0, rb1 = *(const short8*)gb1;

    for (int k = 0; k < 32; ++k) {
        __syncthreads();
        *(short8*)&As[st0] = ra0; *(short8*)&As[st1] = ra1;
        *(short8*)&Bs[st0] = rb0; *(short8*)&Bs[st1] = rb1;
        __syncthreads();
        if (k < 31) {
            ga0 += 32; ga1 += 32; gb0 += 32; gb1 += 32;
            ra0 = *(const short8*)ga0; ra1 = *(const short8*)ga1;
            rb0 = *(const short8*)gb0; rb1 = *(const short8*)gb1;
        }
        short8 af[4], bg[4];
#pragma unroll
        for (int m = 0; m < 4; ++m) af[m] = *(const short8*)&As[offA[m]];
#pragma unroll
        for (int n = 0; n < 4; ++n) bg[n] = *(const short8*)&Bs[offB[n]];
#pragma unroll
        for (int m = 0; m < 4; ++m)
#pragma unroll
            for (int n = 0; n < 4; ++n)
                acc[m][n] = __builtin_amdgcn_mfma_f32_16x16x32_bf16(
                    af[m], bg[n], acc[m][n], 0, 0, 0);
    }

#pragma unroll
    for (int n = 0; n < 4; ++n) {
        const int col = n0 + wc * 64 + n * 16 + fr;
        const float bias = bo[col];
#pragma unroll
        for (int m = 0; m < 4; ++m) {
            const int rowb = m0 + wr * 64 + m * 16 + fq * 4;
#pragma unroll
            for (int r = 0; r < 4; ++r)
                Out[(size_t)(rowb + r) * DEMB + col] = acc[m][n][r] + bias;
        }
    }
}

// ============================================================================
// Flash-style causal attention, fp32 vector math, bf16 I/O.
// Q is pre-scaled (Wq folded). Block = 4 waves, 16x16 thread grid, 4x4
// microtile of a 64x64 S tile. Work-paired grid: block does qt and 31-qt.
// ============================================================================
__global__ __launch_bounds__(256) void flash_attn(
    const unsigned short* __restrict__ Q, const unsigned short* __restrict__ K,
    const unsigned short* __restrict__ V, unsigned short* __restrict__ ctx)
{
    __shared__ float Qs[HD][68]; // [d][r]
    __shared__ float Ks[HD][68]; // [d][c]
    __shared__ float Vs[64][68]; // [kvrow][d]
    __shared__ float Ps[64][68]; // [r][kv]

    const int h = blockIdx.y;
    const int b = blockIdx.z;
    const size_t base = ((size_t)(b * NH + h)) * SEQ * HD;

    const int tid = threadIdx.x;
    const int tx = tid & 15, ty = tid >> 4;

    int rr[4], dd[4];
#pragma unroll
    for (int u = 0; u < 4; ++u) {
        const int f = u * 256 + tid;
        rr[u] = f >> 4;
        dd[u] = (f & 15) * 4;
    }

    for (int half = 0; half < 2; ++half) {
        const int qt = (half == 0) ? (int)blockIdx.x : 31 - (int)blockIdx.x;
        __syncthreads(); // protect Qs across halves

        // ---- load Q tile into Qs[d][r] ----
#pragma unroll
        for (int u = 0; u < 4; ++u) {
            const ushort4 q4 = *(const ushort4*)&Q[base + (size_t)(qt * 64 + rr[u]) * HD + dd[u]];
            Qs[dd[u] + 0][rr[u]] = bf2f(q4.x);
            Qs[dd[u] + 1][rr[u]] = bf2f(q4.y);
            Qs[dd[u] + 2][rr[u]] = bf2f(q4.z);
            Qs[dd[u] + 3][rr[u]] = bf2f(q4.w);
        }

        float m_r[4], l_r[4], o[4][4];
#pragma unroll
        for (int i = 0; i < 4; ++i) {
            m_r[i] = -1e30f;
            l_r[i] = 0.f;
#pragma unroll
            for (int j = 0; j < 4; ++j) o[i][j] = 0.f;
        }

        ushort4 kreg[4], vreg[4];
#pragma unroll
        for (int u = 0; u < 4; ++u) {
            kreg[u] = *(const ushort4*)&K[base + (size_t)(rr[u]) * HD + dd[u]];
            vreg[u] = *(const ushort4*)&V[base + (size_t)(rr[u]) * HD + dd[u]];
        }

        for (int j = 0; j <= qt; ++j) {
            __syncthreads(); // prev PV reads of Ks/Vs/Ps done
#pragma unroll
            for (int u = 0; u < 4; ++u) {
                Ks[dd[u] + 0][rr[u]] = bf2f(kreg[u].x);
                Ks[dd[u] + 1][rr[u]] = bf2f(kreg[u].y);
                Ks[dd[u] + 2][rr[u]] = bf2f(kreg[u].z);
                Ks[dd[u] + 3][rr[u]] = bf2f(kreg[u].w);
                *(float4*)&Vs[rr[u]][dd[u]] = make_float4(
                    bf2f(vreg[u].x), bf2f(vreg[u].y), bf2f(vreg[u].z), bf2f(vreg[u].w));
            }
            __syncthreads();

            // prefetch next K/V tile (hides under QK+softmax+PV)
            if (j < qt) {
#pragma unroll
                for (int u = 0; u < 4; ++u) {
                    kreg[u] = *(const ushort4*)&K[base + (size_t)((j + 1) * 64 + rr[u]) * HD + dd[u]];
                    vreg[u] = *(const ushort4*)&V[base + (size_t)((j + 1) * 64 + rr[u]) * HD + dd[u]];
                }
            }

            // ---- S = Q K^T (Q pre-scaled) ----
            float s[4][4];
#pragma unroll
            for (int i = 0; i < 4; ++i)
#pragma unroll
                for (int jj = 0; jj < 4; ++jj) s[i][jj] = 0.f;
#pragma unroll 16
            for (int d = 0; d < HD; ++d) {
                const float4 a4 = *(const float4*)&Qs[d][ty * 4];
                const float4 b4 = *(const float4*)&Ks[d][tx * 4];
                const float a[4] = {a4.x, a4.y, a4.z, a4.w};
                const float bb[4] = {b4.x, b4.y, b4.z, b4.w};
#pragma unroll
                for (int i = 0; i < 4; ++i)
#pragma unroll
                    for (int jj = 0; jj < 4; ++jj) s[i][jj] += a[i] * bb[jj];
            }
            if (j == qt) {
#pragma unroll
                for (int i = 0; i < 4; ++i)
#pragma unroll
                    for (int jj = 0; jj < 4; ++jj)
                        if (tx * 4 + jj > ty * 4 + i) s[i][jj] = -1e30f;
            }

            // ---- online softmax ----
            float nm[4], rsum[4];
#pragma unroll
            for (int i = 0; i < 4; ++i) {
                float tm = fmaxf(fmaxf(s[i][0], s[i][1]), fmaxf(s[i][2], s[i][3]));
                tm = fmaxf(tm, __shfl_xor(tm, 1, 16));
                tm = fmaxf(tm, __shfl_xor(tm, 2, 16));
                tm = fmaxf(tm, __shfl_xor(tm, 4, 16));
                tm = fmaxf(tm, __shfl_xor(tm, 8, 16));
                nm[i] = fmaxf(m_r[i], tm);
                float rs = 0.f;
#pragma unroll
                for (int jj = 0; jj < 4; ++jj) {
                    const float p = __expf(s[i][jj] - nm[i]);
                    s[i][jj] = p;
                    rs += p;
                }
                rs += __shfl_xor(rs, 1, 16);
                rs += __shfl_xor(rs, 2, 16);
                rs += __shfl_xor(rs, 4, 16);
                rs += __shfl_xor(rs, 8, 16);
                rsum[i] = rs;
            }
#pragma unroll
            for (int i = 0; i < 4; ++i) {
                const float scale = __expf(m_r[i] - nm[i]);
                l_r[i] = l_r[i] * scale + rsum[i];
                m_r[i] = nm[i];
#pragma unroll
                for (int jj = 0; jj < 4; ++jj) o[i][jj] *= scale;
                *(float4*)&Ps[ty * 4 + i][tx * 4] =
                    make_float4(s[i][0], s[i][1], s[i][2], s[i][3]);
            }
            __syncthreads();

            // ---- O += P @ V ----
#pragma unroll 4
            for (int kv0 = 0; kv0 < 64; kv0 += 4) {
                float4 pv[4], vv[4];
#pragma unroll
                for (int i = 0; i < 4; ++i) pv[i] = *(const float4*)&Ps[ty * 4 + i][kv0];
#pragma unroll
                for (int u = 0; u < 4; ++u) vv[u] = *(const float4*)&Vs[kv0 + u][tx * 4];
#pragma unroll
                for (int i = 0; i < 4; ++i) {
                    const float p[4] = {pv[i].x, pv[i].y, pv[i].z, pv[i].w};
#pragma unroll
                    for (int u = 0; u < 4; ++u) {
                        o[i][0] += p[u] * vv[u].x;
                        o[i][1] += p[u] * vv[u].y;
                        o[i][2] += p[u] * vv[u].z;
                        o[i][3] += p[u] * vv[u].w;
                    }
                }
            }
        }

        // ---- epilogue: normalize, write ctx bf16 [b, s, h*64+d] ----
#pragma unroll
        for (int i = 0; i < 4; ++i) {
            const float inv = 1.f / l_r[i];
            const int sg2 = qt * 64 + ty * 4 + i;
            ushort4 o4;
            o4.x = f2bf(o[i][0] * inv);
            o4.y = f2bf(o[i][1] * inv);
            o4.z = f2bf(o[i][2] * inv);
            o4.w = f2bf(o[i][3] * inv);
            *(ushort4*)&ctx[((size_t)(b * SEQ + sg2)) * DEMB + h * HD + tx * 4] = o4;
        }
    }
}

extern "C" void kernel_launch(void* const* d_in, const int* in_sizes, int n_in,
                              void* d_out, int out_size, void* d_ws, size_t ws_size,
                              hipStream_t stream) {
    const float* x  = (const float*)d_in[0];
    const float* Wq = (const float*)d_in[1];
    const float* Wk = (const float*)d_in[2];
    const float* Wv = (const float*)d_in[3];
    const float* Wo = (const float*)d_in[4];
    const float* bo = (const float*)d_in[5];
    float* out = (float*)d_out;

    char* w = (char*)d_ws;
    const size_t MB = 1024 * 1024;
    unsigned short* Qb   = (unsigned short*)(w);            //  8 MB
    unsigned short* Kb   = (unsigned short*)(w + 8  * MB);  //  8 MB
    unsigned short* Vb   = (unsigned short*)(w + 16 * MB);  //  8 MB
    unsigned short* Cb   = (unsigned short*)(w + 24 * MB);  //  8 MB ctx
    unsigned short* Xb   = (unsigned short*)(w + 32 * MB);  //  8 MB
    unsigned short* Wb   = (unsigned short*)(w + 40 * MB);  //  6 MB (q|k|v)
    unsigned short* Wob  = (unsigned short*)(w + 46 * MB);  //  2 MB

    cast_bf16<<<8192, 256, 0, stream>>>(x, Wq, Wk, Wv, Wo, Xb, Wb, Wob);
    gemm_qkv<<<dim3(24, 32), 256, 0, stream>>>(Xb, Wb, Qb, Kb, Vb);
    flash_attn<<<dim3(16, NH, NBATCH), 256, 0, stream>>>(Qb, Kb, Vb, Cb);
    gemm_out<<<dim3(8, 32), 256, 0, stream>>>(Cb, Wob, bo, out);
}

// Round 3
// 262.612 us; speedup vs baseline: 4.0149x; 2.6349x over previous
//
#include <hip/hip_runtime.h>
#include <math.h>

#define SEQ 2048
#define NBATCH 2
#define DEMB 1024
#define NH 16
#define HD 64
#define NROWS (NBATCH * SEQ) // 4096

typedef __attribute__((ext_vector_type(8))) short short8;   // 8 bf16 (4 VGPR)
typedef __attribute__((ext_vector_type(4))) float f32x4;    // MFMA acc

__device__ __forceinline__ unsigned short f2bf(float f) {
    unsigned int u = __float_as_uint(f);
    u = (u + 0x7FFFu + ((u >> 16) & 1u)) >> 16;   // RNE
    return (unsigned short)u;
}
__device__ __forceinline__ unsigned short f2bf_fast(float f) {
    return (unsigned short)((__float_as_uint(f) + 0x8000u) >> 16); // round-half-up
}
__device__ __forceinline__ float bf2f(unsigned short s) {
    return __uint_as_float(((unsigned int)s) << 16);
}

// ============================================================================
// Cast fp32 inputs to bf16 working buffers. Wq pre-scaled by 1/sqrt(HD)=0.125.
// ============================================================================
__global__ __launch_bounds__(256) void cast_bf16(
    const float* __restrict__ x, const float* __restrict__ wq,
    const float* __restrict__ wk, const float* __restrict__ wv,
    const float* __restrict__ wo,
    unsigned short* __restrict__ Xb, unsigned short* __restrict__ Wb,
    unsigned short* __restrict__ Wob)
{
    const int q = blockIdx.x * 256 + threadIdx.x; // quad index
    float4 v; unsigned short* dst; float sc = 1.f;
    if (q < 1048576) {                       // X: 4194304 elems
        v = ((const float4*)x)[q];
        dst = Xb + q * 4;
    } else if (q < 1835008) {                // Wq|Wk|Wv concat: 3145728 elems
        const int e = (q - 1048576) * 4;
        const int which = e >> 20;
        const int off = e & 1048575;
        const float* s = (which == 0) ? wq : (which == 1) ? wk : wv;
        v = *(const float4*)&s[off];
        sc = (which == 0) ? 0.125f : 1.f;
        dst = Wb + e;
    } else {                                 // Wo: 1048576 elems
        const int j = q - 1835008;
        v = ((const float4*)wo)[j];
        dst = Wob + j * 4;
    }
    ushort4 o;
    o.x = f2bf(v.x * sc); o.y = f2bf(v.y * sc);
    o.z = f2bf(v.z * sc); o.w = f2bf(v.w * sc);
    *(ushort4*)dst = o;
}

// ============================================================================
// bf16 MFMA NT-GEMM (m97-lite): 128x128 tile, BK=32, 4 waves, 16x16x32 MFMA.
// QKV variant: A=Xb[4096][1024], B=Wb[3072][1024].
// Q,K written bf16 [b,h,s,d]; V written TRANSPOSED [b,h,d,s] for flash PV.
// ============================================================================
__global__ __launch_bounds__(256) void gemm_qkv(
    const unsigned short* __restrict__ Xb, const unsigned short* __restrict__ Wb,
    unsigned short* __restrict__ Qb, unsigned short* __restrict__ Kb,
    unsigned short* __restrict__ Vtb)
{
    __shared__ __align__(16) short As[128 * 32];
    __shared__ __align__(16) short Bs[128 * 32];

    const int tid = threadIdx.x;
    const int m0 = blockIdx.y * 128, n0 = blockIdx.x * 128;

    const int sr = tid >> 2, sg = tid & 3;
    const int slot = sg ^ ((sr >> 1) & 3);
    const int st0 = sr * 32 + slot * 8;
    const int st1 = (sr + 64) * 32 + slot * 8;

    const int lane = tid & 63, w = tid >> 6;
    const int wr = w >> 1, wc = w & 1;
    const int fr = lane & 15, fq = lane >> 4;

    int offA[4], offB[4];
#pragma unroll
    for (int m = 0; m < 4; ++m) {
        const int rA = wr * 64 + m * 16 + fr;
        offA[m] = rA * 32 + ((fq ^ ((rA >> 1) & 3)) * 8);
        const int rB = wc * 64 + m * 16 + fr;
        offB[m] = rB * 32 + ((fq ^ ((rB >> 1) & 3)) * 8);
    }

    f32x4 acc[4][4];
#pragma unroll
    for (int m = 0; m < 4; ++m)
#pragma unroll
        for (int n = 0; n < 4; ++n) acc[m][n] = (f32x4){0.f, 0.f, 0.f, 0.f};

    const unsigned short* ga0 = Xb + (m0 + sr) * 1024 + sg * 8;
    const unsigned short* ga1 = Xb + (m0 + 64 + sr) * 1024 + sg * 8;
    const unsigned short* gb0 = Wb + (n0 + sr) * 1024 + sg * 8;
    const unsigned short* gb1 = Wb + (n0 + 64 + sr) * 1024 + sg * 8;

    short8 ra0 = *(const short8*)ga0, ra1 = *(const short8*)ga1;
    short8 rb0 = *(const short8*)gb0, rb1 = *(const short8*)gb1;

    for (int k = 0; k < 32; ++k) {
        __syncthreads();
        *(short8*)&As[st0] = ra0; *(short8*)&As[st1] = ra1;
        *(short8*)&Bs[st0] = rb0; *(short8*)&Bs[st1] = rb1;
        __syncthreads();
        if (k < 31) {
            ga0 += 32; ga1 += 32; gb0 += 32; gb1 += 32;
            ra0 = *(const short8*)ga0; ra1 = *(const short8*)ga1;
            rb0 = *(const short8*)gb0; rb1 = *(const short8*)gb1;
        }
        short8 af[4], bg[4];
#pragma unroll
        for (int m = 0; m < 4; ++m) af[m] = *(const short8*)&As[offA[m]];
#pragma unroll
        for (int n = 0; n < 4; ++n) bg[n] = *(const short8*)&Bs[offB[n]];
#pragma unroll
        for (int m = 0; m < 4; ++m)
#pragma unroll
            for (int n = 0; n < 4; ++n)
                acc[m][n] = __builtin_amdgcn_mfma_f32_16x16x32_bf16(
                    af[m], bg[n], acc[m][n], 0, 0, 0);
    }

    // epilogue: C row=(b,s), col->(which,h,d). Q/K: [b,h,s,d]; V: [b,h,d,s].
#pragma unroll
    for (int n = 0; n < 4; ++n) {
        const int col = n0 + wc * 64 + n * 16 + fr;
        const int which = col >> 10;
        const int h = (col >> 6) & 15;
        const int d = col & 63;
#pragma unroll
        for (int m = 0; m < 4; ++m) {
            const int rowb = m0 + wr * 64 + m * 16 + fq * 4;
#pragma unroll
            for (int r = 0; r < 4; ++r) {
                const int row = rowb + r;
                const int b = row >> 11, s = row & 2047;
                const size_t bh = (size_t)b * NH + h;
                const unsigned short val = f2bf(acc[m][n][r]);
                if (which == 0)      Qb [(bh * SEQ + s) * HD + d] = val;
                else if (which == 1) Kb [(bh * SEQ + s) * HD + d] = val;
                else                 Vtb[(bh * HD + d) * SEQ + s] = val;
            }
        }
    }
}

// ============================================================================
// O-projection: ctx_bf16[4096][1024] @ Wob^T + bo -> out fp32 [4096][1024]
// ============================================================================
__global__ __launch_bounds__(256) void gemm_out(
    const unsigned short* __restrict__ Cb, const unsigned short* __restrict__ Wob,
    const float* __restrict__ bo, float* __restrict__ Out)
{
    __shared__ __align__(16) short As[128 * 32];
    __shared__ __align__(16) short Bs[128 * 32];

    const int tid = threadIdx.x;
    const int m0 = blockIdx.y * 128, n0 = blockIdx.x * 128;
    const int sr = tid >> 2, sg = tid & 3;
    const int slot = sg ^ ((sr >> 1) & 3);
    const int st0 = sr * 32 + slot * 8;
    const int st1 = (sr + 64) * 32 + slot * 8;

    const int lane = tid & 63, w = tid >> 6;
    const int wr = w >> 1, wc = w & 1;
    const int fr = lane & 15, fq = lane >> 4;

    int offA[4], offB[4];
#pragma unroll
    for (int m = 0; m < 4; ++m) {
        const int rA = wr * 64 + m * 16 + fr;
        offA[m] = rA * 32 + ((fq ^ ((rA >> 1) & 3)) * 8);
        const int rB = wc * 64 + m * 16 + fr;
        offB[m] = rB * 32 + ((fq ^ ((rB >> 1) & 3)) * 8);
    }

    f32x4 acc[4][4];
#pragma unroll
    for (int m = 0; m < 4; ++m)
#pragma unroll
        for (int n = 0; n < 4; ++n) acc[m][n] = (f32x4){0.f, 0.f, 0.f, 0.f};

    const unsigned short* ga0 = Cb + (m0 + sr) * 1024 + sg * 8;
    const unsigned short* ga1 = Cb + (m0 + 64 + sr) * 1024 + sg * 8;
    const unsigned short* gb0 = Wob + (n0 + sr) * 1024 + sg * 8;
    const unsigned short* gb1 = Wob + (n0 + 64 + sr) * 1024 + sg * 8;

    short8 ra0 = *(const short8*)ga0, ra1 = *(const short8*)ga1;
    short8 rb0 = *(const short8*)gb0, rb1 = *(const short8*)gb1;

    for (int k = 0; k < 32; ++k) {
        __syncthreads();
        *(short8*)&As[st0] = ra0; *(short8*)&As[st1] = ra1;
        *(short8*)&Bs[st0] = rb0; *(short8*)&Bs[st1] = rb1;
        __syncthreads();
        if (k < 31) {
            ga0 += 32; ga1 += 32; gb0 += 32; gb1 += 32;
            ra0 = *(const short8*)ga0; ra1 = *(const short8*)ga1;
            rb0 = *(const short8*)gb0; rb1 = *(const short8*)gb1;
        }
        short8 af[4], bg[4];
#pragma unroll
        for (int m = 0; m < 4; ++m) af[m] = *(const short8*)&As[offA[m]];
#pragma unroll
        for (int n = 0; n < 4; ++n) bg[n] = *(const short8*)&Bs[offB[n]];
#pragma unroll
        for (int m = 0; m < 4; ++m)
#pragma unroll
            for (int n = 0; n < 4; ++n)
                acc[m][n] = __builtin_amdgcn_mfma_f32_16x16x32_bf16(
                    af[m], bg[n], acc[m][n], 0, 0, 0);
    }

#pragma unroll
    for (int n = 0; n < 4; ++n) {
        const int col = n0 + wc * 64 + n * 16 + fr;
        const float bias = bo[col];
#pragma unroll
        for (int m = 0; m < 4; ++m) {
            const int rowb = m0 + wr * 64 + m * 16 + fq * 4;
#pragma unroll
            for (int r = 0; r < 4; ++r)
                Out[(size_t)(rowb + r) * DEMB + col] = acc[m][n][r] + bias;
        }
    }
}

// ============================================================================
// MFMA flash attention. Block = 128 Q rows of one (b,h); 4 waves x 32 rows.
// Q in registers; K [kv][d] and Vt [d][kv] tiles in swizzled LDS; P per-wave
// in swizzled LDS (bf16). Online softmax on C-layout rows.
// LDS swizzle (short units): scol ^= (row&7)<<3  — kills the 16-way conflict
// of 128B-stride row-major tiles (G4/T2); write & read both swizzled.
// ============================================================================
__global__ __launch_bounds__(256) void flash_mfma(
    const unsigned short* __restrict__ Qb, const unsigned short* __restrict__ Kb,
    const unsigned short* __restrict__ Vtb, unsigned short* __restrict__ ctx)
{
    __shared__ __align__(16) short Ks[64 * 64];
    __shared__ __align__(16) short Vs[64 * 64];   // V^T tile [d][kv]
    __shared__ __align__(16) short Ps[4 * 32 * 64]; // per-wave P [32][64]

    const int qt = blockIdx.x;   // 0..15 (128-row Q tiles)
    const int h  = blockIdx.y;
    const int b  = blockIdx.z;
    const size_t bh = (size_t)b * NH + h;
    const unsigned short* __restrict__ Qg = Qb  + bh * SEQ * HD;
    const unsigned short* __restrict__ Kg = Kb  + bh * SEQ * HD;
    const unsigned short* __restrict__ Vg = Vtb + bh * HD * SEQ; // [d][s]

    const int tid = threadIdx.x;
    const int lane = tid & 63, w = tid >> 6;
    const int fr = lane & 15, fq = lane >> 4;

    // staging slots: 512 x 16B per 8KB tile; thread covers rows sr0, sr0+32
    const int sr0 = tid >> 3, sc = tid & 7;
    const int sr1 = sr0 + 32;
    const int ls0 = sr0 * 64 + ((sc * 8) ^ ((sr0 & 7) << 3));
    const int ls1 = sr1 * 64 + ((sc * 8) ^ ((sr1 & 7) << 3));

    const int qbase = qt * 128 + w * 32;   // wave's first Q row
    const int qmaxw = qbase + 31;

    // ---- Q A-fragments in registers ----
    short8 qa[2][2];
#pragma unroll
    for (int m = 0; m < 2; ++m)
#pragma unroll
        for (int ks = 0; ks < 2; ++ks)
            qa[m][ks] = *(const short8*)&Qg[(qbase + m * 16 + fr) * HD + ks * 32 + fq * 8];

    f32x4 o[2][4];
    float mrow[2][4], lrow[2][4];
#pragma unroll
    for (int m = 0; m < 2; ++m)
#pragma unroll
        for (int r = 0; r < 4; ++r) { mrow[m][r] = -3e38f; lrow[m][r] = 0.f; }
#pragma unroll
    for (int m = 0; m < 2; ++m)
#pragma unroll
        for (int n = 0; n < 4; ++n) o[m][n] = (f32x4){0.f, 0.f, 0.f, 0.f};

    short* const Pw = Ps + w * 2048;      // wave-private P region [32][64]

    const int jmax = 2 * qt + 1;

    // prefetch tile 0
    short8 kr0 = *(const short8*)&Kg[(size_t)sr0 * HD + sc * 8];
    short8 kr1 = *(const short8*)&Kg[(size_t)sr1 * HD + sc * 8];
    short8 vr0 = *(const short8*)&Vg[(size_t)sr0 * SEQ + sc * 8];
    short8 vr1 = *(const short8*)&Vg[(size_t)sr1 * SEQ + sc * 8];

    for (int j = 0; j <= jmax; ++j) {
        __syncthreads();   // all reads of previous tile done
        *(short8*)&Ks[ls0] = kr0; *(short8*)&Ks[ls1] = kr1;
        *(short8*)&Vs[ls0] = vr0; *(short8*)&Vs[ls1] = vr1;
        __syncthreads();

        if (j < jmax) {    // prefetch next tile (hidden under compute)
            kr0 = *(const short8*)&Kg[(size_t)((j + 1) * 64 + sr0) * HD + sc * 8];
            kr1 = *(const short8*)&Kg[(size_t)((j + 1) * 64 + sr1) * HD + sc * 8];
            vr0 = *(const short8*)&Vg[(size_t)sr0 * SEQ + (j + 1) * 64 + sc * 8];
            vr1 = *(const short8*)&Vg[(size_t)sr1 * SEQ + (j + 1) * 64 + sc * 8];
        }

        if (j * 64 > qmaxw) continue;   // tile fully masked for this wave

        // ---- S = Q K^T (16 MFMAs) ----
        f32x4 s[2][4];
#pragma unroll
        for (int m = 0; m < 2; ++m)
#pragma unroll
            for (int n = 0; n < 4; ++n) s[m][n] = (f32x4){0.f, 0.f, 0.f, 0.f};
#pragma unroll
        for (int ks = 0; ks < 2; ++ks) {
            short8 kb[4];
#pragma unroll
            for (int n = 0; n < 4; ++n) {
                const int row = n * 16 + fr;
                kb[n] = *(const short8*)&Ks[row * 64 + ((ks * 32 + fq * 8) ^ ((row & 7) << 3))];
            }
#pragma unroll
            for (int m = 0; m < 2; ++m)
#pragma unroll
                for (int n = 0; n < 4; ++n)
                    s[m][n] = __builtin_amdgcn_mfma_f32_16x16x32_bf16(
                        qa[m][ks], kb[n], s[m][n], 0, 0, 0);
        }

        // ---- causal mask on straddling tiles ----
        if (j * 64 + 63 > qbase) {
#pragma unroll
            for (int m = 0; m < 2; ++m) {
                const int qr = qbase + m * 16 + fq * 4;
#pragma unroll
                for (int n = 0; n < 4; ++n) {
                    const int kc = j * 64 + n * 16 + fr;
#pragma unroll
                    for (int r = 0; r < 4; ++r)
                        if (kc > qr + r) s[m][n][r] = -3e38f;
                }
            }
        }

        // ---- online softmax (rows = fq*4+r within each m-frag) ----
#pragma unroll
        for (int m = 0; m < 2; ++m) {
#pragma unroll
            for (int r = 0; r < 4; ++r) {
                float t = fmaxf(fmaxf(s[m][0][r], s[m][1][r]),
                                fmaxf(s[m][2][r], s[m][3][r]));
                t = fmaxf(t, __shfl_xor(t, 1));
                t = fmaxf(t, __shfl_xor(t, 2));
                t = fmaxf(t, __shfl_xor(t, 4));
                t = fmaxf(t, __shfl_xor(t, 8));
                const float nm = fmaxf(mrow[m][r], t);
                const float rescale = __expf(mrow[m][r] - nm);
                mrow[m][r] = nm;
                float rs = 0.f;
#pragma unroll
                for (int n = 0; n < 4; ++n) {
                    const float p = __expf(s[m][n][r] - nm);
                    s[m][n][r] = p;
                    rs += p;
                }
                rs += __shfl_xor(rs, 1);
                rs += __shfl_xor(rs, 2);
                rs += __shfl_xor(rs, 4);
                rs += __shfl_xor(rs, 8);
                lrow[m][r] = lrow[m][r] * rescale + rs;
#pragma unroll
                for (int n = 0; n < 4; ++n) o[m][n][r] *= rescale;
            }
        }

        // ---- P -> wave-private LDS (bf16, swizzled). DS is in-order per
        // wave, so no barrier needed before the same-wave reads below. ----
#pragma unroll
        for (int m = 0; m < 2; ++m)
#pragma unroll
            for (int n = 0; n < 4; ++n)
#pragma unroll
                for (int r = 0; r < 4; ++r) {
                    const int prow = m * 16 + fq * 4 + r;
                    const int pcol = n * 16 + fr;
                    Pw[prow * 64 + (pcol ^ ((prow & 7) << 3))] = f2bf_fast(s[m][n][r]);
                }

        // ---- O += P @ V (16 MFMAs) ----
#pragma unroll
        for (int ks = 0; ks < 2; ++ks) {
            short8 pa[2], vb[4];
#pragma unroll
            for (int m = 0; m < 2; ++m) {
                const int row = m * 16 + fr;
                pa[m] = *(const short8*)&Pw[row * 64 + ((ks * 32 + fq * 8) ^ ((row & 7) << 3))];
            }
#pragma unroll
            for (int n = 0; n < 4; ++n) {
                const int row = n * 16 + fr;   // row = d in Vt
                vb[n] = *(const short8*)&Vs[row * 64 + ((ks * 32 + fq * 8) ^ ((row & 7) << 3))];
            }
#pragma unroll
            for (int m = 0; m < 2; ++m)
#pragma unroll
                for (int n = 0; n < 4; ++n)
                    o[m][n] = __builtin_amdgcn_mfma_f32_16x16x32_bf16(
                        pa[m], vb[n], o[m][n], 0, 0, 0);
        }
    }

    // ---- epilogue: normalize, write ctx bf16 [b, s, h*64+d] ----
#pragma unroll
    for (int m = 0; m < 2; ++m)
#pragma unroll
        for (int r = 0; r < 4; ++r) {
            const float inv = 1.f / lrow[m][r];
            const int rg = qbase + m * 16 + fq * 4 + r;
            const size_t rowoff = ((size_t)b * SEQ + rg) * DEMB + h * HD;
#pragma unroll
            for (int n = 0; n < 4; ++n)
                ctx[rowoff + n * 16 + fr] = f2bf(o[m][n][r] * inv);
        }
}

extern "C" void kernel_launch(void* const* d_in, const int* in_sizes, int n_in,
                              void* d_out, int out_size, void* d_ws, size_t ws_size,
                              hipStream_t stream) {
    const float* x  = (const float*)d_in[0];
    const float* Wq = (const float*)d_in[1];
    const float* Wk = (const float*)d_in[2];
    const float* Wv = (const float*)d_in[3];
    const float* Wo = (const float*)d_in[4];
    const float* bo = (const float*)d_in[5];
    float* out = (float*)d_out;

    char* w = (char*)d_ws;
    const size_t MB = 1024 * 1024;
    unsigned short* Qb   = (unsigned short*)(w);            //  8 MB
    unsigned short* Kb   = (unsigned short*)(w + 8  * MB);  //  8 MB
    unsigned short* Vtb  = (unsigned short*)(w + 16 * MB);  //  8 MB  [b,h,d,s]
    unsigned short* Cb   = (unsigned short*)(w + 24 * MB);  //  8 MB ctx
    unsigned short* Xb   = (unsigned short*)(w + 32 * MB);  //  8 MB
    unsigned short* Wb   = (unsigned short*)(w + 40 * MB);  //  6 MB (q|k|v)
    unsigned short* Wob  = (unsigned short*)(w + 46 * MB);  //  2 MB

    cast_bf16<<<8192, 256, 0, stream>>>(x, Wq, Wk, Wv, Wo, Xb, Wb, Wob);
    gemm_qkv<<<dim3(24, 32), 256, 0, stream>>>(Xb, Wb, Qb, Kb, Vtb);
    flash_mfma<<<dim3(16, NH, NBATCH), 256, 0, stream>>>(Qb, Kb, Vtb, Cb);
    gemm_out<<<dim3(8, 32), 256, 0, stream>>>(Cb, Wob, bo, out);
}

// Round 4
// 203.258 us; speedup vs baseline: 5.1873x; 1.2920x over previous
//
#include <hip/hip_runtime.h>
#include <math.h>

#define SEQ 2048
#define NBATCH 2
#define DEMB 1024
#define NH 16
#define HD 64
#define NROWS (NBATCH * SEQ) // 4096

typedef __attribute__((ext_vector_type(8))) short short8;   // 8 bf16 (4 VGPR)
typedef __attribute__((ext_vector_type(4))) float f32x4;    // MFMA acc

__device__ __forceinline__ unsigned short f2bf(float f) {
    unsigned int u = __float_as_uint(f);
    u = (u + 0x7FFFu + ((u >> 16) & 1u)) >> 16;   // RNE
    return (unsigned short)u;
}
__device__ __forceinline__ unsigned short f2bf_fast(float f) {
    return (unsigned short)((__float_as_uint(f) + 0x8000u) >> 16); // round-half-up
}

// ============================================================================
// Cast fp32 inputs to bf16. Wq pre-scaled by 0.125*log2(e) so attention
// softmax runs in the exp2 domain with no extra multiplies.
// ============================================================================
__global__ __launch_bounds__(256) void cast_bf16(
    const float* __restrict__ x, const float* __restrict__ wq,
    const float* __restrict__ wk, const float* __restrict__ wv,
    const float* __restrict__ wo,
    unsigned short* __restrict__ Xb, unsigned short* __restrict__ Wb,
    unsigned short* __restrict__ Wob)
{
    const int q = blockIdx.x * 256 + threadIdx.x; // quad index
    float4 v; unsigned short* dst; float sc = 1.f;
    if (q < 1048576) {                       // X: 4194304 elems
        v = ((const float4*)x)[q];
        dst = Xb + q * 4;
    } else if (q < 1835008) {                // Wq|Wk|Wv concat: 3145728 elems
        const int e = (q - 1048576) * 4;
        const int which = e >> 20;
        const int off = e & 1048575;
        const float* s = (which == 0) ? wq : (which == 1) ? wk : wv;
        v = *(const float4*)&s[off];
        sc = (which == 0) ? 0.18033688011112042f : 1.f;  // 0.125*log2(e)
        dst = Wb + e;
    } else {                                 // Wo: 1048576 elems
        const int j = q - 1835008;
        v = ((const float4*)wo)[j];
        dst = Wob + j * 4;
    }
    ushort4 o;
    o.x = f2bf(v.x * sc); o.y = f2bf(v.y * sc);
    o.z = f2bf(v.z * sc); o.w = f2bf(v.w * sc);
    *(ushort4*)dst = o;
}

// ============================================================================
// bf16 MFMA NT-GEMM: 128x128 tile, BK=32, 4 waves, 16x16x32 MFMA.
// A=Xb[4096][1024], B=Wb[3072][1024]. Q,K,V all written bf16 [b,h,s,d]
// (coalesced-ish scalar stores; V transposed later by transpose_v).
// ============================================================================
__global__ __launch_bounds__(256) void gemm_qkv(
    const unsigned short* __restrict__ Xb, const unsigned short* __restrict__ Wb,
    unsigned short* __restrict__ Qb, unsigned short* __restrict__ Kb,
    unsigned short* __restrict__ Vb)
{
    __shared__ __align__(16) short As[128 * 32];
    __shared__ __align__(16) short Bs[128 * 32];

    const int tid = threadIdx.x;
    const int m0 = blockIdx.y * 128, n0 = blockIdx.x * 128;

    const int sr = tid >> 2, sg = tid & 3;
    const int slot = sg ^ ((sr >> 1) & 3);
    const int st0 = sr * 32 + slot * 8;
    const int st1 = (sr + 64) * 32 + slot * 8;

    const int lane = tid & 63, w = tid >> 6;
    const int wr = w >> 1, wc = w & 1;
    const int fr = lane & 15, fq = lane >> 4;

    int offA[4], offB[4];
#pragma unroll
    for (int m = 0; m < 4; ++m) {
        const int rA = wr * 64 + m * 16 + fr;
        offA[m] = rA * 32 + ((fq ^ ((rA >> 1) & 3)) * 8);
        const int rB = wc * 64 + m * 16 + fr;
        offB[m] = rB * 32 + ((fq ^ ((rB >> 1) & 3)) * 8);
    }

    f32x4 acc[4][4];
#pragma unroll
    for (int m = 0; m < 4; ++m)
#pragma unroll
        for (int n = 0; n < 4; ++n) acc[m][n] = (f32x4){0.f, 0.f, 0.f, 0.f};

    const unsigned short* ga0 = Xb + (m0 + sr) * 1024 + sg * 8;
    const unsigned short* ga1 = Xb + (m0 + 64 + sr) * 1024 + sg * 8;
    const unsigned short* gb0 = Wb + (n0 + sr) * 1024 + sg * 8;
    const unsigned short* gb1 = Wb + (n0 + 64 + sr) * 1024 + sg * 8;

    short8 ra0 = *(const short8*)ga0, ra1 = *(const short8*)ga1;
    short8 rb0 = *(const short8*)gb0, rb1 = *(const short8*)gb1;

    for (int k = 0; k < 32; ++k) {
        __syncthreads();
        *(short8*)&As[st0] = ra0; *(short8*)&As[st1] = ra1;
        *(short8*)&Bs[st0] = rb0; *(short8*)&Bs[st1] = rb1;
        __syncthreads();
        if (k < 31) {
            ga0 += 32; ga1 += 32; gb0 += 32; gb1 += 32;
            ra0 = *(const short8*)ga0; ra1 = *(const short8*)ga1;
            rb0 = *(const short8*)gb0; rb1 = *(const short8*)gb1;
        }
        short8 af[4], bg[4];
#pragma unroll
        for (int m = 0; m < 4; ++m) af[m] = *(const short8*)&As[offA[m]];
#pragma unroll
        for (int n = 0; n < 4; ++n) bg[n] = *(const short8*)&Bs[offB[n]];
        __builtin_amdgcn_s_setprio(1);
#pragma unroll
        for (int m = 0; m < 4; ++m)
#pragma unroll
            for (int n = 0; n < 4; ++n)
                acc[m][n] = __builtin_amdgcn_mfma_f32_16x16x32_bf16(
                    af[m], bg[n], acc[m][n], 0, 0, 0);
        __builtin_amdgcn_s_setprio(0);
    }

#pragma unroll
    for (int n = 0; n < 4; ++n) {
        const int col = n0 + wc * 64 + n * 16 + fr;
        const int which = col >> 10;
        const int h = (col >> 6) & 15;
        const int d = col & 63;
        unsigned short* Out = (which == 0) ? Qb : (which == 1) ? Kb : Vb;
#pragma unroll
        for (int m = 0; m < 4; ++m) {
            const int rowb = m0 + wr * 64 + m * 16 + fq * 4;
#pragma unroll
            for (int r = 0; r < 4; ++r) {
                const int row = rowb + r;
                const int b = row >> 11, s = row & 2047;
                Out[(((size_t)b * NH + h) * SEQ + s) * HD + d] =
                    f2bf(acc[m][n][r]);
            }
        }
    }
}

// ============================================================================
// V [b,h,s,d] -> Vt [b,h,d,s] via LDS tile (both global sides coalesced).
// ============================================================================
__global__ __launch_bounds__(256) void transpose_v(
    const unsigned short* __restrict__ Vb, unsigned short* __restrict__ Vtb)
{
    __shared__ short T[64][72];   // pad 72 spreads banks across rows
    const int s0tile = blockIdx.x * 64;
    const size_t bh = blockIdx.y;
    const unsigned short* src = Vb + bh * SEQ * HD;
    unsigned short* dst = Vtb + bh * (size_t)HD * SEQ;
    const int t = threadIdx.x;
    const int sr = t >> 3, sc = t & 7;   // 32 rows x 8 colgroups

    const short8 a = *(const short8*)&src[(size_t)(s0tile + sr) * HD + sc * 8];
    const short8 bb = *(const short8*)&src[(size_t)(s0tile + sr + 32) * HD + sc * 8];
    *(short8*)&T[sr][sc * 8] = a;
    *(short8*)&T[sr + 32][sc * 8] = bb;
    __syncthreads();

    const int d = t >> 2, s0 = (t & 3) * 16;
    short8 o0, o1;
#pragma unroll
    for (int i = 0; i < 8; ++i) {
        o0[i] = T[s0 + i][d];
        o1[i] = T[s0 + 8 + i][d];
    }
    *(short8*)&dst[(size_t)d * SEQ + s0tile + s0] = o0;
    *(short8*)&dst[(size_t)d * SEQ + s0tile + s0 + 8] = o1;
}

// ============================================================================
// MFMA flash attention, swapped-QK^T softmax + defer-max + wave-paired balance.
// 256 blocks x 512 threads. Waves 0-3: Q-tile qtA=bx; waves 4-7: qtB=15-bx.
// Shared K/Vt staging (64kv x 64d, XOR-swizzled). Per wave: 32 Q rows.
// S^T = mfma(K,Q): lane holds 2 full q-rows (16 kv vals each) -> row reduce =
// in-lane max/sum + 2 shfl_xor (vs 64 shfls in the naive layout).
// ============================================================================
__global__ __launch_bounds__(512) void flash_mfma2(
    const unsigned short* __restrict__ Qb, const unsigned short* __restrict__ Kb,
    const unsigned short* __restrict__ Vtb, unsigned short* __restrict__ ctx)
{
    __shared__ __align__(16) short Ks[64 * 64];
    __shared__ __align__(16) short Vs[64 * 64];     // Vt tile [d][kv]
    __shared__ __align__(16) short Ps[8 * 32 * 64]; // per-wave P [32 q][64 kv]

    const int bx = blockIdx.x;   // 0..7
    const int h  = blockIdx.y;
    const int b  = blockIdx.z;
    const size_t bh = (size_t)b * NH + h;
    const unsigned short* __restrict__ Qg = Qb  + bh * SEQ * HD;
    const unsigned short* __restrict__ Kg = Kb  + bh * SEQ * HD;
    const unsigned short* __restrict__ Vg = Vtb + bh * (size_t)HD * SEQ;

    const int tid = threadIdx.x;
    const int lane = tid & 63, w = tid >> 6;
    const int fr = lane & 15, fq = lane >> 4;

    const int qtB = 15 - bx;
    const int qt_eff = (w < 4) ? bx : qtB;
    const int qbase = qt_eff * 128 + (w & 3) * 32;
    const int qmaxw = qbase + 31;
    const int jstage = 2 * qtB + 1;          // qtB >= qtA always

    // staging: 512 threads cover one short8 of K-tile and one of V-tile
    const int sr = tid >> 3, sc = tid & 7;
    const int lsw = sr * 64 + ((sc * 8) ^ ((sr & 7) << 3));

    // Q fragments (reused as MFMA B-operand)
    short8 qa[2][2];
#pragma unroll
    for (int m = 0; m < 2; ++m)
#pragma unroll
        for (int ks = 0; ks < 2; ++ks)
            qa[m][ks] = *(const short8*)&Qg[(qbase + m * 16 + fr) * HD + ks * 32 + fq * 8];

    f32x4 o[2][4];
    float mold[2], lsum[2];
#pragma unroll
    for (int m = 0; m < 2; ++m) {
        mold[m] = -3e38f; lsum[m] = 0.f;
#pragma unroll
        for (int n = 0; n < 4; ++n) o[m][n] = (f32x4){0.f, 0.f, 0.f, 0.f};
    }

    short* const Pw = Ps + w * 2048;

    short8 kr = *(const short8*)&Kg[(size_t)sr * HD + sc * 8];
    short8 vr = *(const short8*)&Vg[(size_t)sr * SEQ + sc * 8];

    for (int j = 0; j <= jstage; ++j) {
        __syncthreads();
        *(short8*)&Ks[lsw] = kr;
        *(short8*)&Vs[lsw] = vr;
        __syncthreads();
        if (j < jstage) {
            kr = *(const short8*)&Kg[(size_t)((j + 1) * 64 + sr) * HD + sc * 8];
            vr = *(const short8*)&Vg[(size_t)sr * SEQ + (j + 1) * 64 + sc * 8];
        }
        if (j * 64 > qmaxw) continue;   // tile fully masked for this wave

        // ---- S^T = K Q^T : st[n][m], lane holds q-col = m*16+fr ----
        f32x4 st[4][2];
#pragma unroll
        for (int n = 0; n < 4; ++n)
#pragma unroll
            for (int m = 0; m < 2; ++m) st[n][m] = (f32x4){0.f, 0.f, 0.f, 0.f};
#pragma unroll
        for (int ks = 0; ks < 2; ++ks) {
            short8 kf[4];
#pragma unroll
            for (int n = 0; n < 4; ++n) {
                const int row = n * 16 + fr;
                kf[n] = *(const short8*)&Ks[row * 64 + ((ks * 32 + fq * 8) ^ ((row & 7) << 3))];
            }
            __builtin_amdgcn_s_setprio(1);
#pragma unroll
            for (int n = 0; n < 4; ++n)
#pragma unroll
                for (int m = 0; m < 2; ++m)
                    st[n][m] = __builtin_amdgcn_mfma_f32_16x16x32_bf16(
                        kf[n], qa[m][ks], st[n][m], 0, 0, 0);
            __builtin_amdgcn_s_setprio(0);
        }

        // ---- causal mask (kv = j*64+n*16+fq*4+r, q = qbase+m*16+fr) ----
        if (j * 64 + 63 > qbase) {
#pragma unroll
            for (int n = 0; n < 4; ++n) {
                const int kv = j * 64 + n * 16 + fq * 4;
#pragma unroll
                for (int m = 0; m < 2; ++m) {
                    const int q = qbase + m * 16 + fr;
#pragma unroll
                    for (int r = 0; r < 4; ++r)
                        if (kv + r > q) st[n][m][r] = -3e38f;
                }
            }
        }

        // ---- row max (in-lane 16 + 2 shfl across fq partners) ----
        float pmax[2];
#pragma unroll
        for (int m = 0; m < 2; ++m) {
            float t0 = fmaxf(fmaxf(st[0][m][0], st[0][m][1]), fmaxf(st[0][m][2], st[0][m][3]));
            float t1 = fmaxf(fmaxf(st[1][m][0], st[1][m][1]), fmaxf(st[1][m][2], st[1][m][3]));
            float t2 = fmaxf(fmaxf(st[2][m][0], st[2][m][1]), fmaxf(st[2][m][2], st[2][m][3]));
            float t3 = fmaxf(fmaxf(st[3][m][0], st[3][m][1]), fmaxf(st[3][m][2], st[3][m][3]));
            float t = fmaxf(fmaxf(t0, t1), fmaxf(t2, t3));
            t = fmaxf(t, __shfl_xor(t, 16));
            t = fmaxf(t, __shfl_xor(t, 32));
            pmax[m] = t;
        }

        // ---- defer-max (T13): skip rescale unless max grew > 8 (log2 units)
        const float growth = fmaxf(pmax[0] - mold[0], pmax[1] - mold[1]);
        if (!__all(growth <= 8.0f)) {
            float resc[2];
#pragma unroll
            for (int m = 0; m < 2; ++m) {
                const float nm = fmaxf(mold[m], pmax[m]);
                resc[m] = exp2f(mold[m] - nm);
                mold[m] = nm;
                lsum[m] *= resc[m];
            }
            // redistribute rescale to PV layout rows (q = m*16 + fq*4 + rr)
#pragma unroll
            for (int m = 0; m < 2; ++m)
#pragma unroll
                for (int rr = 0; rr < 4; ++rr) {
                    const float rsc = __shfl(resc[m], fq * 4 + rr);
#pragma unroll
                    for (int n = 0; n < 4; ++n) o[m][n][rr] *= rsc;
                }
        }

        // ---- exp2, row-sum, P -> wave-private LDS (bf16, swizzled) ----
#pragma unroll
        for (int m = 0; m < 2; ++m) {
            float rs = 0.f;
            const int prow = m * 16 + fr;
            const int swz = (fr & 7) << 3;
#pragma unroll
            for (int n = 0; n < 4; ++n)
#pragma unroll
                for (int r = 0; r < 4; ++r) {
                    const float p = exp2f(st[n][m][r] - mold[m]);
                    rs += p;
                    Pw[prow * 64 + ((n * 16 + fq * 4 + r) ^ swz)] = f2bf_fast(p);
                }
            rs += __shfl_xor(rs, 16);
            rs += __shfl_xor(rs, 32);
            lsum[m] += rs;
        }

        // ---- O += P @ Vt (DS in-order per wave: no barrier needed) ----
#pragma unroll
        for (int ks = 0; ks < 2; ++ks) {
            short8 pa[2], vb[4];
#pragma unroll
            for (int m = 0; m < 2; ++m) {
                const int row = m * 16 + fr;
                pa[m] = *(const short8*)&Pw[row * 64 + ((ks * 32 + fq * 8) ^ ((row & 7) << 3))];
            }
#pragma unroll
            for (int n = 0; n < 4; ++n) {
                const int row = n * 16 + fr;   // d-row in Vt
                vb[n] = *(const short8*)&Vs[row * 64 + ((ks * 32 + fq * 8) ^ ((row & 7) << 3))];
            }
            __builtin_amdgcn_s_setprio(1);
#pragma unroll
            for (int m = 0; m < 2; ++m)
#pragma unroll
                for (int n = 0; n < 4; ++n)
                    o[m][n] = __builtin_amdgcn_mfma_f32_16x16x32_bf16(
                        pa[m], vb[n], o[m][n], 0, 0, 0);
            __builtin_amdgcn_s_setprio(0);
        }
    }

    // ---- epilogue: normalize (l redistributed), write ctx [b,s,h*64+d] ----
#pragma unroll
    for (int m = 0; m < 2; ++m)
#pragma unroll
        for (int rr = 0; rr < 4; ++rr) {
            const float lv = __shfl(lsum[m], fq * 4 + rr);
            const float inv = 1.f / lv;
            const int q = qbase + m * 16 + fq * 4 + rr;
            const size_t rowoff = ((size_t)b * SEQ + q) * DEMB + h * HD;
#pragma unroll
            for (int n = 0; n < 4; ++n)
                ctx[rowoff + n * 16 + fr] = f2bf(o[m][n][rr] * inv);
        }
}

// ============================================================================
// O-projection: ctx_bf16[4096][1024] @ Wob^T + bo -> out fp32 [4096][1024]
// ============================================================================
__global__ __launch_bounds__(256) void gemm_out(
    const unsigned short* __restrict__ Cb, const unsigned short* __restrict__ Wob,
    const float* __restrict__ bo, float* __restrict__ Out)
{
    __shared__ __align__(16) short As[128 * 32];
    __shared__ __align__(16) short Bs[128 * 32];

    const int tid = threadIdx.x;
    const int m0 = blockIdx.y * 128, n0 = blockIdx.x * 128;
    const int sr = tid >> 2, sg = tid & 3;
    const int slot = sg ^ ((sr >> 1) & 3);
    const int st0 = sr * 32 + slot * 8;
    const int st1 = (sr + 64) * 32 + slot * 8;

    const int lane = tid & 63, w = tid >> 6;
    const int wr = w >> 1, wc = w & 1;
    const int fr = lane & 15, fq = lane >> 4;

    int offA[4], offB[4];
#pragma unroll
    for (int m = 0; m < 4; ++m) {
        const int rA = wr * 64 + m * 16 + fr;
        offA[m] = rA * 32 + ((fq ^ ((rA >> 1) & 3)) * 8);
        const int rB = wc * 64 + m * 16 + fr;
        offB[m] = rB * 32 + ((fq ^ ((rB >> 1) & 3)) * 8);
    }

    f32x4 acc[4][4];
#pragma unroll
    for (int m = 0; m < 4; ++m)
#pragma unroll
        for (int n = 0; n < 4; ++n) acc[m][n] = (f32x4){0.f, 0.f, 0.f, 0.f};

    const unsigned short* ga0 = Cb + (m0 + sr) * 1024 + sg * 8;
    const unsigned short* ga1 = Cb + (m0 + 64 + sr) * 1024 + sg * 8;
    const unsigned short* gb0 = Wob + (n0 + sr) * 1024 + sg * 8;
    const unsigned short* gb1 = Wob + (n0 + 64 + sr) * 1024 + sg * 8;

    short8 ra0 = *(const short8*)ga0, ra1 = *(const short8*)ga1;
    short8 rb0 = *(const short8*)gb0, rb1 = *(const short8*)gb1;

    for (int k = 0; k < 32; ++k) {
        __syncthreads();
        *(short8*)&As[st0] = ra0; *(short8*)&As[st1] = ra1;
        *(short8*)&Bs[st0] = rb0; *(short8*)&Bs[st1] = rb1;
        __syncthreads();
        if (k < 31) {
            ga0 += 32; ga1 += 32; gb0 += 32; gb1 += 32;
            ra0 = *(const short8*)ga0; ra1 = *(const short8*)ga1;
            rb0 = *(const short8*)gb0; rb1 = *(const short8*)gb1;
        }
        short8 af[4], bg[4];
#pragma unroll
        for (int m = 0; m < 4; ++m) af[m] = *(const short8*)&As[offA[m]];
#pragma unroll
        for (int n = 0; n < 4; ++n) bg[n] = *(const short8*)&Bs[offB[n]];
        __builtin_amdgcn_s_setprio(1);
#pragma unroll
        for (int m = 0; m < 4; ++m)
#pragma unroll
            for (int n = 0; n < 4; ++n)
                acc[m][n] = __builtin_amdgcn_mfma_f32_16x16x32_bf16(
                    af[m], bg[n], acc[m][n], 0, 0, 0);
        __builtin_amdgcn_s_setprio(0);
    }

#pragma unroll
    for (int n = 0; n < 4; ++n) {
        const int col = n0 + wc * 64 + n * 16 + fr;
        const float bias = bo[col];
#pragma unroll
        for (int m = 0; m < 4; ++m) {
            const int rowb = m0 + wr * 64 + m * 16 + fq * 4;
#pragma unroll
            for (int r = 0; r < 4; ++r)
                Out[(size_t)(rowb + r) * DEMB + col] = acc[m][n][r] + bias;
        }
    }
}

extern "C" void kernel_launch(void* const* d_in, const int* in_sizes, int n_in,
                              void* d_out, int out_size, void* d_ws, size_t ws_size,
                              hipStream_t stream) {
    const float* x  = (const float*)d_in[0];
    const float* Wq = (const float*)d_in[1];
    const float* Wk = (const float*)d_in[2];
    const float* Wv = (const float*)d_in[3];
    const float* Wo = (const float*)d_in[4];
    const float* bo = (const float*)d_in[5];
    float* out = (float*)d_out;

    char* w = (char*)d_ws;
    const size_t MB = 1024 * 1024;
    unsigned short* Qb   = (unsigned short*)(w);            //  8 MB
    unsigned short* Kb   = (unsigned short*)(w + 8  * MB);  //  8 MB
    unsigned short* Vb   = (unsigned short*)(w + 16 * MB);  //  8 MB [b,h,s,d]
    unsigned short* Cb   = (unsigned short*)(w + 24 * MB);  //  8 MB ctx
    unsigned short* Xb   = (unsigned short*)(w + 32 * MB);  //  8 MB (dead after gemm_qkv)
    unsigned short* Wb   = (unsigned short*)(w + 40 * MB);  //  6 MB (q|k|v)
    unsigned short* Wob  = (unsigned short*)(w + 46 * MB);  //  2 MB
    unsigned short* Vtb  = Xb;                              //  reuse: [b,h,d,s]

    cast_bf16<<<8192, 256, 0, stream>>>(x, Wq, Wk, Wv, Wo, Xb, Wb, Wob);
    gemm_qkv<<<dim3(24, 32), 256, 0, stream>>>(Xb, Wb, Qb, Kb, Vb);
    transpose_v<<<dim3(SEQ / 64, NBATCH * NH), 256, 0, stream>>>(Vb, Vtb);
    flash_mfma2<<<dim3(8, NH, NBATCH), 512, 0, stream>>>(Qb, Kb, Vtb, Cb);
    gemm_out<<<dim3(8, 32), 256, 0, stream>>>(Cb, Wob, bo, out);
}